// Round 1
// baseline (972.293 us; speedup 1.0000x reference)
//
#include <hip/hip_runtime.h>

#define BN_EPS 1e-5f

// ---------------- CSR build ----------------

__global__ void count_kernel(const int* __restrict__ ei, int* __restrict__ counts, int E) {
    int e = blockIdx.x * blockDim.x + threadIdx.x;
    if (e < E) atomicAdd(&counts[ei[E + e]], 1);
}

__global__ void isd_kernel(const int* __restrict__ counts, float* __restrict__ isd, int N) {
    int n = blockIdx.x * blockDim.x + threadIdx.x;
    if (n < N) isd[n] = rsqrtf((float)counts[n] + 1.0f);
}

// single-block exclusive scan of counts -> rowptr[0..N], chunk = 256 threads * 8
__global__ void scan_kernel(const int* __restrict__ counts, int* __restrict__ rowptr, int n) {
    const int tid = threadIdx.x;
    const int lane = tid & 63, wave = tid >> 6;
    __shared__ int wsum[4];
    __shared__ int s_carry;
    if (tid == 0) s_carry = 0;
    __syncthreads();
    for (int base = 0; base < n; base += 2048) {
        int idx0 = base + tid * 8;
        int v[8];
        int tsum = 0;
#pragma unroll
        for (int j = 0; j < 8; j++) {
            int i = idx0 + j;
            v[j] = (i < n) ? counts[i] : 0;
            tsum += v[j];
        }
        int incl = tsum;
#pragma unroll
        for (int off = 1; off < 64; off <<= 1) {
            int t = __shfl_up(incl, off, 64);
            if (lane >= off) incl += t;
        }
        if (lane == 63) wsum[wave] = incl;
        __syncthreads();
        int wexcl = 0;
        for (int w2 = 0; w2 < wave; w2++) wexcl += wsum[w2];
        int carry = s_carry;
        __syncthreads();
        int run = carry + wexcl + (incl - tsum);
#pragma unroll
        for (int j = 0; j < 8; j++) {
            int i = idx0 + j;
            if (i < n) rowptr[i] = run;
            run += v[j];
        }
        if (tid == 255) s_carry = run;
        __syncthreads();
    }
    if (tid == 0) rowptr[n] = s_carry;
}

__global__ void scatter_kernel(const int* __restrict__ ei, const int* __restrict__ rowptr,
                               int* __restrict__ cursor, const float* __restrict__ isd,
                               int* __restrict__ srcs, float* __restrict__ coefs, int E) {
    int e = blockIdx.x * blockDim.x + threadIdx.x;
    if (e < E) {
        int s = ei[e], d = ei[E + e];
        int p = atomicAdd(&cursor[d], 1);
        int idx = rowptr[d] + p;
        srcs[idx] = s;
        coefs[idx] = isd[s] * isd[d];
    }
}

// ---------------- encoder: h0 = relu(x @ Wenc + benc), + BN partial stats ----------------

__global__ __launch_bounds__(256) void encoder_kernel(const float* __restrict__ x,
                                                      const float* __restrict__ W,
                                                      const float* __restrict__ b,
                                                      float* __restrict__ h0,
                                                      float* __restrict__ partials, int N) {
    int tid = threadIdx.x;
    int g = blockIdx.x * 256 + tid;
    int total = gridDim.x * 256;
    int c = tid & 127;
    float w0 = W[c], w1 = W[128 + c], w2 = W[256 + c], w3 = W[384 + c], bb = b[c];
    float s = 0.f, q = 0.f;
    int tot = N * 128;
    for (int i = g; i < tot; i += total) {
        int n = i >> 7;
        float4 xv = ((const float4*)x)[n];
        float v = fmaf(xv.x, w0, fmaf(xv.y, w1, fmaf(xv.z, w2, fmaf(xv.w, w3, bb))));
        v = fmaxf(v, 0.f);
        h0[i] = v;
        s += v;
        q += v * v;
    }
    __shared__ float ls[256];
    ls[tid] = s;
    __syncthreads();
    if (tid < 128) partials[blockIdx.x * 256 + tid] = ls[tid] + ls[tid + 128];
    __syncthreads();
    ls[tid] = q;
    __syncthreads();
    if (tid < 128) partials[blockIdx.x * 256 + 128 + tid] = ls[tid] + ls[tid + 128];
}

// ---------------- BN stats reduction ----------------

__global__ void reduce_partials(const float* __restrict__ partials, float* __restrict__ partials2,
                                int nrows) {
    int c = threadIdx.x;
    int per = nrows >> 8;
    int r0 = blockIdx.x * per;
    float s = 0.f;
    for (int r = r0; r < r0 + per; ++r) s += partials[r * 256 + c];
    partials2[blockIdx.x * 256 + c] = s;
}

__global__ void finalize_stats(const float* __restrict__ partials2, const float* __restrict__ g,
                               const float* __restrict__ beta, float* __restrict__ ss, float invN) {
    int tid = threadIdx.x;
    float s = 0.f;
    for (int r = 0; r < 256; ++r) s += partials2[r * 256 + tid];
    __shared__ float sh[256];
    sh[tid] = s;
    __syncthreads();
    if (tid < 128) {
        float S = sh[tid], Q = sh[tid + 128];
        float mu = S * invN;
        float var = Q * invN - mu * mu;
        float rs = rsqrtf(var + BN_EPS);
        float scale = g[tid] * rs;
        ss[tid] = scale;
        ss[128 + tid] = beta[tid] - mu * scale;
    }
}

// ---------------- tiled f32 GEMM: C[N,NOUT] = A[N,K] @ B[K,NOUT] (+bias, relu) ----------------

template <int NOUT, int K, bool RELU>
__global__ __launch_bounds__(256) void gemm_kernel(const float* __restrict__ A,
                                                   const float* __restrict__ B,
                                                   const float* __restrict__ bias,
                                                   float* __restrict__ C, int N) {
    constexpr int TN = NOUT / 16;
    __shared__ float As[64 * 17];
    __shared__ float Bs[16 * NOUT];
    const int tid = threadIdx.x;
    const int tx = tid & 15, ty = tid >> 4;
    const int row0 = blockIdx.x * 64;
    float acc[4][TN];
#pragma unroll
    for (int i = 0; i < 4; i++)
#pragma unroll
        for (int j = 0; j < TN; j++) acc[i][j] = 0.f;

    for (int k0 = 0; k0 < K; k0 += 16) {
        {
            int r = tid >> 2, c4 = (tid & 3) * 4;
            int grow = row0 + r;
            float4 v = make_float4(0.f, 0.f, 0.f, 0.f);
            if (grow < N) v = *(const float4*)&A[(size_t)grow * K + k0 + c4];
            As[r * 17 + c4 + 0] = v.x;
            As[r * 17 + c4 + 1] = v.y;
            As[r * 17 + c4 + 2] = v.z;
            As[r * 17 + c4 + 3] = v.w;
        }
        {
            constexpr int tot4 = 16 * NOUT / 4;
            for (int f = tid; f < tot4; f += 256) {
                int r = f / (NOUT / 4);
                int c4 = (f % (NOUT / 4)) * 4;
                *(float4*)&Bs[r * NOUT + c4] = *(const float4*)&B[(size_t)(k0 + r) * NOUT + c4];
            }
        }
        __syncthreads();
#pragma unroll
        for (int kk = 0; kk < 16; ++kk) {
            float a[4], bf[TN];
#pragma unroll
            for (int i = 0; i < 4; i++) a[i] = As[(ty * 4 + i) * 17 + kk];
#pragma unroll
            for (int j = 0; j < TN; j++) bf[j] = Bs[kk * NOUT + tx + 16 * j];
#pragma unroll
            for (int i = 0; i < 4; i++)
#pragma unroll
                for (int j = 0; j < TN; j++) acc[i][j] = fmaf(a[i], bf[j], acc[i][j]);
        }
        __syncthreads();
    }
#pragma unroll
    for (int i = 0; i < 4; i++) {
        int grow = row0 + ty * 4 + i;
        if (grow < N) {
#pragma unroll
            for (int j = 0; j < TN; j++) {
                int c = tx + 16 * j;
                float v = acc[i][j];
                if (bias) v += bias[c];
                if (RELU) v = fmaxf(v, 0.f);
                C[(size_t)grow * NOUT + c] = v;
            }
        }
    }
}

// ---------------- aggregation: agg[n] = sum_in-edges hw[src]*coef + hw[n]*isd[n]^2, + stats ----------------

__global__ __launch_bounds__(256) void agg_kernel(const float* __restrict__ hw,
                                                  const int* __restrict__ rowptr,
                                                  const int* __restrict__ srcs,
                                                  const float* __restrict__ coefs,
                                                  const float* __restrict__ isd,
                                                  float* __restrict__ agg,
                                                  float* __restrict__ partials, int N) {
    int tid = threadIdx.x;
    int wave = tid >> 6, lane = tid & 63;
    int c0 = lane << 1;
    float s0 = 0.f, s1 = 0.f, q0 = 0.f, q1 = 0.f;
    for (int n = blockIdx.x * 4 + wave; n < N; n += gridDim.x * 4) {
        int e0 = rowptr[n], e1 = rowptr[n + 1];
        float isdn = isd[n];
        const float2 hv = *(const float2*)&hw[(size_t)n * 128 + c0];
        float a0 = hv.x * isdn * isdn, a1 = hv.y * isdn * isdn;
        for (int e = e0; e < e1; ++e) {
            int sn = srcs[e];
            float w = coefs[e];
            const float2 v = *(const float2*)&hw[(size_t)sn * 128 + c0];
            a0 = fmaf(v.x, w, a0);
            a1 = fmaf(v.y, w, a1);
        }
        *(float2*)&agg[(size_t)n * 128 + c0] = make_float2(a0, a1);
        s0 += a0;
        s1 += a1;
        q0 += a0 * a0;
        q1 += a1 * a1;
    }
    __shared__ float ls[4][128];
    ls[wave][c0] = s0;
    ls[wave][c0 + 1] = s1;
    __syncthreads();
    if (tid < 128)
        partials[blockIdx.x * 256 + tid] = ls[0][tid] + ls[1][tid] + ls[2][tid] + ls[3][tid];
    __syncthreads();
    ls[wave][c0] = q0;
    ls[wave][c0 + 1] = q1;
    __syncthreads();
    if (tid < 128)
        partials[blockIdx.x * 256 + 128 + tid] = ls[0][tid] + ls[1][tid] + ls[2][tid] + ls[3][tid];
}

// ---------------- elementwise ----------------

// h = h*scale + shift (encoder BN apply)
__global__ void norm_kernel(float* __restrict__ h, const float* __restrict__ ss, int total4) {
    int g = blockIdx.x * blockDim.x + threadIdx.x;
    int stride = gridDim.x * blockDim.x;
    for (int i = g; i < total4; i += stride) {
        int c = (i << 2) & 127;
        float4 v = ((const float4*)h)[i];
        float4 sc = *(const float4*)&ss[c];
        float4 sb = *(const float4*)&ss[128 + c];
        v.x = fmaf(v.x, sc.x, sb.x);
        v.y = fmaf(v.y, sc.y, sb.y);
        v.z = fmaf(v.z, sc.z, sb.z);
        v.w = fmaf(v.w, sc.w, sb.w);
        ((float4*)h)[i] = v;
    }
}

// h += relu(agg*scale + shift)
__global__ void update_kernel(float* __restrict__ h, const float* __restrict__ agg,
                              const float* __restrict__ ss, int total4) {
    int g = blockIdx.x * blockDim.x + threadIdx.x;
    int stride = gridDim.x * blockDim.x;
    for (int i = g; i < total4; i += stride) {
        int c = (i << 2) & 127;
        float4 a = ((const float4*)agg)[i];
        float4 hv = ((const float4*)h)[i];
        float4 sc = *(const float4*)&ss[c];
        float4 sb = *(const float4*)&ss[128 + c];
        hv.x += fmaxf(fmaf(a.x, sc.x, sb.x), 0.f);
        hv.y += fmaxf(fmaf(a.y, sc.y, sb.y), 0.f);
        hv.z += fmaxf(fmaf(a.z, sc.z, sb.z), 0.f);
        hv.w += fmaxf(fmaf(a.w, sc.w, sb.w), 0.f);
        ((float4*)h)[i] = hv;
    }
}

// ---------------- decoder final: out = d2 @ W3 + b3 ----------------

__global__ void dec3_kernel(const float* __restrict__ d2, const float* __restrict__ W3,
                            const float* __restrict__ b3, float* __restrict__ out, int N) {
    __shared__ float tile[64 * 33];
    __shared__ float w3s[32];
    int base = blockIdx.x * 64;
    int tid = threadIdx.x;
    if (tid < 32) w3s[tid] = W3[tid];
    for (int f = tid; f < 2048; f += 256) {
        int r = f >> 5, c = f & 31;
        int n = base + r;
        tile[r * 33 + c] = (n < N) ? d2[(size_t)n * 32 + c] : 0.f;
    }
    __syncthreads();
    if (tid < 64) {
        int n = base + tid;
        if (n < N) {
            float s = b3[0];
#pragma unroll
            for (int k = 0; k < 32; k++) s = fmaf(tile[tid * 33 + k], w3s[k], s);
            out[n] = s;
        }
    }
}

// ---------------- host ----------------

extern "C" void kernel_launch(void* const* d_in, const int* in_sizes, int n_in, void* d_out,
                              int out_size, void* d_ws, size_t ws_size, hipStream_t stream) {
    const float* x = (const float*)d_in[0];
    const int* ei = (const int*)d_in[1];
    const float* enc_w = (const float*)d_in[2];
    const float* enc_b = (const float*)d_in[3];
    const float* enc_bn_g = (const float*)d_in[4];
    const float* enc_bn_b = (const float*)d_in[5];
    const float* conv_w = (const float*)d_in[6];
    // d_in[7] = conv_b: per-channel constant added before BatchNorm -> cancels exactly, unused
    const float* bn_g = (const float*)d_in[8];
    const float* bn_b = (const float*)d_in[9];
    const float* dw1 = (const float*)d_in[10];
    const float* db1 = (const float*)d_in[11];
    const float* dw2 = (const float*)d_in[12];
    const float* db2 = (const float*)d_in[13];
    const float* dw3 = (const float*)d_in[14];
    const float* db3 = (const float*)d_in[15];
    float* out = (float*)d_out;

    const int N = in_sizes[0] / 4;   // 50000
    const int E = in_sizes[1] / 2;   // 600000
    const size_t N128 = (size_t)N * 128;

    // workspace layout (~86 MB)
    float* h = (float*)d_ws;
    float* hw = h + N128;
    float* agg = hw + N128;
    float* partials = agg + N128;           // 2048*256
    float* partials2 = partials + 2048 * 256;  // 256*256
    float* ss = partials2 + 256 * 256;      // 256: scale[128], shift[128]
    float* isd = ss + 256;                  // N
    int* counts = (int*)(isd + N);          // N
    int* rowptr = counts + N;               // N+1
    int* cursor = rowptr + N + 1;           // N
    int* srcs = cursor + N;                 // E
    float* coefs = (float*)(srcs + E);      // E
    float* d1 = hw;                         // reuse after conv layers: N x 64
    float* d2 = agg;                        // reuse: N x 32

    hipMemsetAsync(counts, 0, (size_t)N * sizeof(int), stream);
    hipMemsetAsync(cursor, 0, (size_t)N * sizeof(int), stream);

    const int eb = (E + 255) / 256;
    count_kernel<<<eb, 256, 0, stream>>>(ei, counts, E);
    isd_kernel<<<(N + 255) / 256, 256, 0, stream>>>(counts, isd, N);
    scan_kernel<<<1, 256, 0, stream>>>(counts, rowptr, N);
    scatter_kernel<<<eb, 256, 0, stream>>>(ei, rowptr, cursor, isd, srcs, coefs, E);

    encoder_kernel<<<2048, 256, 0, stream>>>(x, enc_w, enc_b, h, partials, N);
    reduce_partials<<<256, 256, 0, stream>>>(partials, partials2, 2048);
    finalize_stats<<<1, 256, 0, stream>>>(partials2, enc_bn_g, enc_bn_b, ss, 1.0f / N);
    norm_kernel<<<2048, 256, 0, stream>>>(h, ss, (int)(N128 / 4));

    const int gblocks = (N + 63) / 64;
    for (int l = 0; l < 6; l++) {
        gemm_kernel<128, 128, false>
            <<<gblocks, 256, 0, stream>>>(h, conv_w + (size_t)l * 128 * 128, nullptr, hw, N);
        agg_kernel<<<2048, 256, 0, stream>>>(hw, rowptr, srcs, coefs, isd, agg, partials, N);
        reduce_partials<<<256, 256, 0, stream>>>(partials, partials2, 2048);
        finalize_stats<<<1, 256, 0, stream>>>(partials2, bn_g + l * 128, bn_b + l * 128, ss,
                                              1.0f / N);
        update_kernel<<<2048, 256, 0, stream>>>(h, agg, ss, (int)(N128 / 4));
    }

    gemm_kernel<64, 128, true><<<gblocks, 256, 0, stream>>>(h, dw1, db1, d1, N);
    gemm_kernel<32, 64, true><<<gblocks, 256, 0, stream>>>(d1, dw2, db2, d2, N);
    dec3_kernel<<<gblocks, 256, 0, stream>>>(d2, dw3, db3, out, N);
}